// Round 1
// baseline (1089.361 us; speedup 1.0000x reference)
//
#include <hip/hip_runtime.h>

// Shapes are fixed by the problem: B = IN = OUT = 512; T derived from out_size.
// Reformulation: v_t = P_t @ x^T  [OUT, B];  G = x @ x^T  [B, B]
//   u_t   = k * (M * e^{-t} + a * v_t)           (M = relu(x@W^T+b)^T, [OUT,B])
//   h_t   = (u_t > 0);  s_t = (u_t > V_th)
//   v_{t+1} = d * v_t + e * ( h_t @ G + bt * colsum(G) )
// Row r of v evolves independently -> block-local recurrence, no grid sync.

#define NN 512

// ---- Kernel A: M[r,b] = relu(x[b,:]·W[r,:] + bias[r]);  V0[r,b] = x[b,:]·P0[r,:]
__global__ __launch_bounds__(256) void mlp_v0_kernel(
    const float* __restrict__ x, const float* __restrict__ W,
    const float* __restrict__ bias, const float* __restrict__ P0,
    float* __restrict__ M, float* __restrict__ V0)
{
    __shared__ float Wl[NN];
    __shared__ float Pl[NN];
    const int r = blockIdx.x;
    const int j = threadIdx.x;
    Wl[j]       = W[r * NN + j];
    Wl[j + 256] = W[r * NN + j + 256];
    Pl[j]       = P0[r * NN + j];
    Pl[j + 256] = P0[r * NN + j + 256];
    __syncthreads();
    const float br = bias[r];
    for (int bb = j; bb < NN; bb += 256) {
        const float4* xr = (const float4*)(x + (size_t)bb * NN);
        float dw = 0.f, dp = 0.f;
#pragma unroll 8
        for (int i = 0; i < NN / 4; ++i) {
            float4 xv = xr[i];
            float4 wv = *(const float4*)(Wl + 4 * i);
            float4 pv = *(const float4*)(Pl + 4 * i);
            dw += xv.x * wv.x + xv.y * wv.y + xv.z * wv.z + xv.w * wv.w;
            dp += xv.x * pv.x + xv.y * pv.y + xv.z * pv.z + xv.w * pv.w;
        }
        M[r * NN + bb]  = fmaxf(dw + br, 0.f);
        V0[r * NN + bb] = dp;
    }
}

// ---- Kernel B: G[b1,b2] = x[b1,:]·x[b2,:]
__global__ __launch_bounds__(256) void gram_kernel(
    const float* __restrict__ x, float* __restrict__ G)
{
    __shared__ float xl[NN];
    const int b1 = blockIdx.x;
    const int j = threadIdx.x;
    xl[j]       = x[b1 * NN + j];
    xl[j + 256] = x[b1 * NN + j + 256];
    __syncthreads();
    for (int b2 = j; b2 < NN; b2 += 256) {
        const float4* xr = (const float4*)(x + (size_t)b2 * NN);
        float dg = 0.f;
#pragma unroll 8
        for (int i = 0; i < NN / 4; ++i) {
            float4 xv = xr[i];
            float4 lv = *(const float4*)(xl + 4 * i);
            dg += xv.x * lv.x + xv.y * lv.y + xv.z * lv.z + xv.w * lv.w;
        }
        G[b1 * NN + b2] = dg;
    }
}

// ---- Kernel C: gs[c] = sum over rows of G[:, c]
__global__ __launch_bounds__(256) void colsum_kernel(
    const float* __restrict__ G, float* __restrict__ gs)
{
    const int c = blockIdx.x * 256 + threadIdx.x;
    float s = 0.f;
    for (int bp = 0; bp < NN; ++bp) s += G[bp * NN + c];
    gs[c] = s;
}

// ---- Main persistent kernel: 256 blocks x 256 threads; block owns rows 2*bid, 2*bid+1;
// thread owns columns 2j, 2j+1. State v kept in registers.
__global__ __launch_bounds__(256) void snn_step_kernel(
    const float* __restrict__ M, const float* __restrict__ G,
    const float* __restrict__ V0, const float* __restrict__ gs,
    const float* __restrict__ alpha, const float* __restrict__ eta,
    const float* __restrict__ beta, float* __restrict__ out, int T)
{
    const int j = threadIdx.x;
    const int r0 = blockIdx.x * 2;
    const int c0 = 2 * j;
    const float a = alpha[0];
    const float e = eta[0];
    const float bt = beta[0];
    const float kk = 0.2f;                    // dt / tao_u
    const float dd = 0.36787944117144233f;    // exp(-dt/tao_w) == exp(-1)
    const float Vth = 0.2f;

    float v00 = V0[r0 * NN + c0];
    float v01 = V0[r0 * NN + c0 + 1];
    float v10 = V0[(r0 + 1) * NN + c0];
    float v11 = V0[(r0 + 1) * NN + c0 + 1];
    const float m00 = M[r0 * NN + c0];
    const float m01 = M[r0 * NN + c0 + 1];
    const float m10 = M[(r0 + 1) * NN + c0];
    const float m11 = M[(r0 + 1) * NN + c0 + 1];
    const float gs0 = gs[c0];
    const float gs1 = gs[c0 + 1];

    __shared__ float2 hp[NN];   // hp[b'] = (h[r0][b'], h[r0+1][b'])

    float em = 1.0f;            // exp(-t)
    const float2* Gcol = (const float2*)G + j;   // float2 index: bp*256 + j -> cols (2j, 2j+1)

    for (int t = 0; t < T; ++t) {
        const float u00 = kk * (m00 * em + a * v00);
        const float u01 = kk * (m01 * em + a * v01);
        const float u10 = kk * (m10 * em + a * v10);
        const float u11 = kk * (m11 * em + a * v11);

        // emit spikes: out[t, b, r] -> rows r0, r0+1 are adjacent -> float2 store
        float* outp = out + (size_t)t * (NN * NN);
        float2 sA = make_float2(u00 > Vth ? 1.f : 0.f, u10 > Vth ? 1.f : 0.f);
        float2 sB = make_float2(u01 > Vth ? 1.f : 0.f, u11 > Vth ? 1.f : 0.f);
        *(float2*)(outp + (size_t)c0 * NN + r0) = sA;
        *(float2*)(outp + (size_t)(c0 + 1) * NN + r0) = sB;

        hp[c0]     = make_float2(u00 > 0.f ? 1.f : 0.f, u10 > 0.f ? 1.f : 0.f);
        hp[c0 + 1] = make_float2(u01 > 0.f ? 1.f : 0.f, u11 > 0.f ? 1.f : 0.f);
        __syncthreads();

        float acc00 = 0.f, acc01 = 0.f, acc10 = 0.f, acc11 = 0.f;
#pragma unroll 8
        for (int bp = 0; bp < NN; ++bp) {
            float2 h = hp[bp];            // LDS broadcast
            float2 g = Gcol[(size_t)bp * 256];  // coalesced 8B/lane
            acc00 = fmaf(h.x, g.x, acc00);
            acc01 = fmaf(h.x, g.y, acc01);
            acc10 = fmaf(h.y, g.x, acc10);
            acc11 = fmaf(h.y, g.y, acc11);
        }

        v00 = dd * v00 + e * (acc00 + bt * gs0);
        v01 = dd * v01 + e * (acc01 + bt * gs1);
        v10 = dd * v10 + e * (acc10 + bt * gs0);
        v11 = dd * v11 + e * (acc11 + bt * gs1);
        em *= dd;
        __syncthreads();   // protect hp before next-step overwrite
    }
}

extern "C" void kernel_launch(void* const* d_in, const int* in_sizes, int n_in,
                              void* d_out, int out_size, void* d_ws, size_t ws_size,
                              hipStream_t stream)
{
    const float* x     = (const float*)d_in[0];
    const float* W     = (const float*)d_in[1];
    const float* bias  = (const float*)d_in[2];
    const float* alpha = (const float*)d_in[3];
    const float* eta   = (const float*)d_in[4];
    const float* beta  = (const float*)d_in[5];
    const float* P0    = (const float*)d_in[6];
    (void)in_sizes; (void)n_in; (void)ws_size;

    const int T = out_size / (NN * NN);

    float* ws  = (float*)d_ws;
    float* M   = ws;                    // [512, 512]  (OUT, B)
    float* G   = ws + NN * NN;          // [512, 512]  (B, B)
    float* V0  = ws + 2 * NN * NN;      // [512, 512]  (OUT, B)
    float* gsv = ws + 3 * NN * NN;      // [512]

    hipLaunchKernelGGL(mlp_v0_kernel, dim3(NN), dim3(256), 0, stream, x, W, bias, P0, M, V0);
    hipLaunchKernelGGL(gram_kernel,   dim3(NN), dim3(256), 0, stream, x, G);
    hipLaunchKernelGGL(colsum_kernel, dim3(2),  dim3(256), 0, stream, G, gsv);
    hipLaunchKernelGGL(snn_step_kernel, dim3(256), dim3(256), 0, stream,
                       M, G, V0, gsv, alpha, eta, beta, (float*)d_out, T);
}

// Round 2
// 520.680 us; speedup vs baseline: 2.0922x; 2.0922x over previous
//
#include <hip/hip_runtime.h>

// B = IN = OUT = 512; T from out_size.
// v_t = P_t @ x^T [OUT,B]; G = x@x^T [B,B]
//   u = k*(M*e^{-t} + a*v);  h = (u>0);  s = (u>0.2)
//   v' = d*v + e*(h@G + bt*colsum(G))
// h binary -> h@G = sum of selected G rows. Quad-table trick:
//   tab[idx][q][c] = sum_{i: idx>>i&1} G[4q+i][c]   (16 x 128 x 512 f32 = 4 MB)
// Per row per step: 128 table-row reads instead of 512 G-row reads (2x L2 traffic cut,
// 4x FLOP cut, multiplies become adds).

#define NN 512

// ---- Kernel A: M[r,b] = relu(x[b,:]·W[r,:] + bias[r]);  V0[r,b] = x[b,:]·P0[r,:]
__global__ __launch_bounds__(256) void mlp_v0_kernel(
    const float* __restrict__ x, const float* __restrict__ W,
    const float* __restrict__ bias, const float* __restrict__ P0,
    float* __restrict__ M, float* __restrict__ V0)
{
    __shared__ float Wl[NN];
    __shared__ float Pl[NN];
    const int r = blockIdx.x;
    const int j = threadIdx.x;
    Wl[j]       = W[r * NN + j];
    Wl[j + 256] = W[r * NN + j + 256];
    Pl[j]       = P0[r * NN + j];
    Pl[j + 256] = P0[r * NN + j + 256];
    __syncthreads();
    const float br = bias[r];
    for (int bb = j; bb < NN; bb += 256) {
        const float4* xr = (const float4*)(x + (size_t)bb * NN);
        float dw = 0.f, dp = 0.f;
#pragma unroll 8
        for (int i = 0; i < NN / 4; ++i) {
            float4 xv = xr[i];
            float4 wv = *(const float4*)(Wl + 4 * i);
            float4 pv = *(const float4*)(Pl + 4 * i);
            dw += xv.x * wv.x + xv.y * wv.y + xv.z * wv.z + xv.w * wv.w;
            dp += xv.x * pv.x + xv.y * pv.y + xv.z * pv.z + xv.w * pv.w;
        }
        M[r * NN + bb]  = fmaxf(dw + br, 0.f);
        V0[r * NN + bb] = dp;
    }
}

// ---- Kernel B: G[b1,b2] = x[b1,:]·x[b2,:]
__global__ __launch_bounds__(256) void gram_kernel(
    const float* __restrict__ x, float* __restrict__ G)
{
    __shared__ float xl[NN];
    const int b1 = blockIdx.x;
    const int j = threadIdx.x;
    xl[j]       = x[b1 * NN + j];
    xl[j + 256] = x[b1 * NN + j + 256];
    __syncthreads();
    for (int b2 = j; b2 < NN; b2 += 256) {
        const float4* xr = (const float4*)(x + (size_t)b2 * NN);
        float dg = 0.f;
#pragma unroll 8
        for (int i = 0; i < NN / 4; ++i) {
            float4 xv = xr[i];
            float4 lv = *(const float4*)(xl + 4 * i);
            dg += xv.x * lv.x + xv.y * lv.y + xv.z * lv.z + xv.w * lv.w;
        }
        G[b1 * NN + b2] = dg;
    }
}

// ---- Kernel C: gs[c] = colsum of G
__global__ __launch_bounds__(256) void colsum_kernel(
    const float* __restrict__ G, float* __restrict__ gs)
{
    const int c = blockIdx.x * 256 + threadIdx.x;
    float s = 0.f;
    for (int bp = 0; bp < NN; ++bp) s += G[bp * NN + c];
    gs[c] = s;
}

// ---- Kernel D: quad table. tab[((idx*128)+q)*512 + c]
__global__ __launch_bounds__(256) void build_table_kernel(
    const float* __restrict__ G, float* __restrict__ tab)
{
    const int q = blockIdx.x;        // 0..127
    const int j = threadIdx.x;       // 0..255
    for (int c = j; c < NN; c += 256) {
        const float g0 = G[(4 * q + 0) * NN + c];
        const float g1 = G[(4 * q + 1) * NN + c];
        const float g2 = G[(4 * q + 2) * NN + c];
        const float g3 = G[(4 * q + 3) * NN + c];
#pragma unroll
        for (int idx = 0; idx < 16; ++idx) {
            float val = 0.f;
            if (idx & 1) val += g0;
            if (idx & 2) val += g1;
            if (idx & 4) val += g2;
            if (idx & 8) val += g3;
            tab[(((size_t)idx * 128 + q) << 9) + c] = val;
        }
    }
}

// ---- Main: 512 blocks (1 row each) x 128 threads (4 cols each, float4).
__global__ __launch_bounds__(128) void snn_quad_kernel(
    const float* __restrict__ M, const float* __restrict__ tab,
    const float* __restrict__ V0, const float* __restrict__ gs,
    const float* __restrict__ alpha, const float* __restrict__ eta,
    const float* __restrict__ beta, float* __restrict__ out, int T)
{
    const int l = threadIdx.x;        // 0..127
    const int r = blockIdx.x;         // row
    const int c0 = 4 * l;
    const float a = alpha[0];
    const float e = eta[0];
    const float bt = beta[0];
    const float kk = 0.2f;                    // dt / tao_u
    const float dd = 0.36787944117144233f;    // exp(-1)
    const float Vth = 0.2f;

    float4 v = *(const float4*)(V0 + (size_t)r * NN + c0);
    const float4 m = *(const float4*)(M + (size_t)r * NN + c0);
    const float4 g4 = *(const float4*)(gs + c0);
    // constant additive term e*bt*gs
    float4 cg;
    cg.x = e * bt * g4.x; cg.y = e * bt * g4.y;
    cg.z = e * bt * g4.z; cg.w = e * bt * g4.w;

    __shared__ uint4 idxq[2][8];      // 2 x 128 idx bytes, 16B-aligned

    const float* tb = tab + c0;       // + idx*65536 + q*512
    float em = 1.0f;
    int p = 0;

    for (int t = 0; t < T; ++t) {
        float4 u;
        u.x = kk * fmaf(a, v.x, m.x * em);
        u.y = kk * fmaf(a, v.y, m.y * em);
        u.z = kk * fmaf(a, v.z, m.z * em);
        u.w = kk * fmaf(a, v.w, m.w * em);

        // spikes: out[t][c][r], 4 scalar stores stride 512 floats
        float* op = out + (size_t)t * (NN * NN) + (size_t)c0 * NN + r;
        op[0]        = u.x > Vth ? 1.f : 0.f;
        op[NN]       = u.y > Vth ? 1.f : 0.f;
        op[2 * NN]   = u.z > Vth ? 1.f : 0.f;
        op[3 * NN]   = u.w > Vth ? 1.f : 0.f;

        // quad index for this thread's 4 cols (= quad l): bit i <-> col 4l+i
        unsigned idx = (u.x > 0.f ? 1u : 0u) | (u.y > 0.f ? 2u : 0u)
                     | (u.z > 0.f ? 4u : 0u) | (u.w > 0.f ? 8u : 0u);
        ((unsigned char*)&idxq[p][0])[l] = (unsigned char)idx;
        __syncthreads();

        float4 acc = make_float4(0.f, 0.f, 0.f, 0.f);
#pragma unroll
        for (int g = 0; g < 4; ++g) {          // 4 groups of 32 quads
            const uint4 wa = idxq[p][2 * g];
            const uint4 wb = idxq[p][2 * g + 1];
            const unsigned wz[8] = {wa.x, wa.y, wa.z, wa.w, wb.x, wb.y, wb.z, wb.w};
#pragma unroll
            for (int d = 0; d < 8; ++d) {
                const unsigned w = wz[d];
#pragma unroll
                for (int k = 0; k < 4; ++k) {
                    const int q = 32 * g + 4 * d + k;
                    const unsigned ib = (w >> (8 * k)) & 0xFFu;
                    const float4 tv = *(const float4*)(tb + ((size_t)ib << 16) + (q << 9));
                    acc.x += tv.x; acc.y += tv.y; acc.z += tv.z; acc.w += tv.w;
                }
            }
        }

        v.x = fmaf(dd, v.x, fmaf(e, acc.x, cg.x));
        v.y = fmaf(dd, v.y, fmaf(e, acc.y, cg.y));
        v.z = fmaf(dd, v.z, fmaf(e, acc.z, cg.z));
        v.w = fmaf(dd, v.w, fmaf(e, acc.w, cg.w));
        em *= dd;
        p ^= 1;
        // no second barrier: next step writes the OTHER idx buffer
    }
}

// ---- Round-1 fallback kernel (if ws too small for the 4 MB table)
__global__ __launch_bounds__(256) void snn_step_kernel(
    const float* __restrict__ M, const float* __restrict__ G,
    const float* __restrict__ V0, const float* __restrict__ gs,
    const float* __restrict__ alpha, const float* __restrict__ eta,
    const float* __restrict__ beta, float* __restrict__ out, int T)
{
    const int j = threadIdx.x;
    const int r0 = blockIdx.x * 2;
    const int c0 = 2 * j;
    const float a = alpha[0];
    const float e = eta[0];
    const float bt = beta[0];
    const float kk = 0.2f;
    const float dd = 0.36787944117144233f;
    const float Vth = 0.2f;

    float v00 = V0[r0 * NN + c0];
    float v01 = V0[r0 * NN + c0 + 1];
    float v10 = V0[(r0 + 1) * NN + c0];
    float v11 = V0[(r0 + 1) * NN + c0 + 1];
    const float m00 = M[r0 * NN + c0];
    const float m01 = M[r0 * NN + c0 + 1];
    const float m10 = M[(r0 + 1) * NN + c0];
    const float m11 = M[(r0 + 1) * NN + c0 + 1];
    const float gs0 = gs[c0];
    const float gs1 = gs[c0 + 1];

    __shared__ float2 hp[NN];
    float em = 1.0f;
    const float2* Gcol = (const float2*)G + j;

    for (int t = 0; t < T; ++t) {
        const float u00 = kk * (m00 * em + a * v00);
        const float u01 = kk * (m01 * em + a * v01);
        const float u10 = kk * (m10 * em + a * v10);
        const float u11 = kk * (m11 * em + a * v11);

        float* outp = out + (size_t)t * (NN * NN);
        float2 sA = make_float2(u00 > Vth ? 1.f : 0.f, u10 > Vth ? 1.f : 0.f);
        float2 sB = make_float2(u01 > Vth ? 1.f : 0.f, u11 > Vth ? 1.f : 0.f);
        *(float2*)(outp + (size_t)c0 * NN + r0) = sA;
        *(float2*)(outp + (size_t)(c0 + 1) * NN + r0) = sB;

        hp[c0]     = make_float2(u00 > 0.f ? 1.f : 0.f, u10 > 0.f ? 1.f : 0.f);
        hp[c0 + 1] = make_float2(u01 > 0.f ? 1.f : 0.f, u11 > 0.f ? 1.f : 0.f);
        __syncthreads();

        float acc00 = 0.f, acc01 = 0.f, acc10 = 0.f, acc11 = 0.f;
#pragma unroll 8
        for (int bp = 0; bp < NN; ++bp) {
            float2 h = hp[bp];
            float2 g = Gcol[(size_t)bp * 256];
            acc00 = fmaf(h.x, g.x, acc00);
            acc01 = fmaf(h.x, g.y, acc01);
            acc10 = fmaf(h.y, g.x, acc10);
            acc11 = fmaf(h.y, g.y, acc11);
        }

        v00 = dd * v00 + e * (acc00 + bt * gs0);
        v01 = dd * v01 + e * (acc01 + bt * gs1);
        v10 = dd * v10 + e * (acc10 + bt * gs0);
        v11 = dd * v11 + e * (acc11 + bt * gs1);
        em *= dd;
        __syncthreads();
    }
}

extern "C" void kernel_launch(void* const* d_in, const int* in_sizes, int n_in,
                              void* d_out, int out_size, void* d_ws, size_t ws_size,
                              hipStream_t stream)
{
    const float* x     = (const float*)d_in[0];
    const float* W     = (const float*)d_in[1];
    const float* bias  = (const float*)d_in[2];
    const float* alpha = (const float*)d_in[3];
    const float* eta   = (const float*)d_in[4];
    const float* beta  = (const float*)d_in[5];
    const float* P0    = (const float*)d_in[6];
    (void)in_sizes; (void)n_in;

    const int T = out_size / (NN * NN);

    float* ws  = (float*)d_ws;
    float* M   = ws;                    // [512,512]
    float* G   = ws + NN * NN;          // [512,512]
    float* V0  = ws + 2 * NN * NN;      // [512,512]
    float* gsv = ws + 3 * NN * NN;      // [512]
    float* tab = ws + 3 * NN * NN + NN; // [16][128][512] = 4 MB

    const size_t needed = ((size_t)3 * NN * NN + NN + (size_t)16 * 128 * 512) * 4;

    hipLaunchKernelGGL(mlp_v0_kernel, dim3(NN), dim3(256), 0, stream, x, W, bias, P0, M, V0);
    hipLaunchKernelGGL(gram_kernel,   dim3(NN), dim3(256), 0, stream, x, G);
    hipLaunchKernelGGL(colsum_kernel, dim3(2),  dim3(256), 0, stream, G, gsv);

    if (ws_size >= needed) {
        hipLaunchKernelGGL(build_table_kernel, dim3(128), dim3(256), 0, stream, G, tab);
        hipLaunchKernelGGL(snn_quad_kernel, dim3(NN), dim3(128), 0, stream,
                           M, tab, V0, gsv, alpha, eta, beta, (float*)d_out, T);
    } else {
        hipLaunchKernelGGL(snn_step_kernel, dim3(256), dim3(256), 0, stream,
                           M, G, V0, gsv, alpha, eta, beta, (float*)d_out, T);
    }
}

// Round 3
// 463.070 us; speedup vs baseline: 2.3525x; 1.1244x over previous
//
#include <hip/hip_runtime.h>

// B = IN = OUT = 512; T from out_size.
// v_t = P_t @ x^T [OUT,B]; G = x@x^T [B,B]
//   u = k*(M*e^{-t} + a*v);  h = (u>0);  s = (u>0.2)
//   v' = d*v + e*(h@G + bt*colsum(G))
// h binary -> h@G via quad table: tab[idx][q][c] (16 x 128 x 512 f32 = 4 MB).
// Spikes packed to bits in step kernel (2 MB scratch), expanded to f32 [T,B,OUT]
// by a coalesced transpose/expand kernel (kills the 10x write amplification).

#define NN 512

// ---- Kernel A: M[r,b] = relu(x[b,:]·W[r,:] + bias[r]);  V0[r,b] = x[b,:]·P0[r,:]
__global__ __launch_bounds__(256) void mlp_v0_kernel(
    const float* __restrict__ x, const float* __restrict__ W,
    const float* __restrict__ bias, const float* __restrict__ P0,
    float* __restrict__ M, float* __restrict__ V0)
{
    __shared__ float Wl[NN];
    __shared__ float Pl[NN];
    const int r = blockIdx.x;
    const int j = threadIdx.x;
    Wl[j]       = W[r * NN + j];
    Wl[j + 256] = W[r * NN + j + 256];
    Pl[j]       = P0[r * NN + j];
    Pl[j + 256] = P0[r * NN + j + 256];
    __syncthreads();
    const float br = bias[r];
    for (int bb = j; bb < NN; bb += 256) {
        const float4* xr = (const float4*)(x + (size_t)bb * NN);
        float dw = 0.f, dp = 0.f;
#pragma unroll 8
        for (int i = 0; i < NN / 4; ++i) {
            float4 xv = xr[i];
            float4 wv = *(const float4*)(Wl + 4 * i);
            float4 pv = *(const float4*)(Pl + 4 * i);
            dw += xv.x * wv.x + xv.y * wv.y + xv.z * wv.z + xv.w * wv.w;
            dp += xv.x * pv.x + xv.y * pv.y + xv.z * pv.z + xv.w * pv.w;
        }
        M[r * NN + bb]  = fmaxf(dw + br, 0.f);
        V0[r * NN + bb] = dp;
    }
}

// ---- Kernel B: G[b1,b2] = x[b1,:]·x[b2,:]
__global__ __launch_bounds__(256) void gram_kernel(
    const float* __restrict__ x, float* __restrict__ G)
{
    __shared__ float xl[NN];
    const int b1 = blockIdx.x;
    const int j = threadIdx.x;
    xl[j]       = x[b1 * NN + j];
    xl[j + 256] = x[b1 * NN + j + 256];
    __syncthreads();
    for (int b2 = j; b2 < NN; b2 += 256) {
        const float4* xr = (const float4*)(x + (size_t)b2 * NN);
        float dg = 0.f;
#pragma unroll 8
        for (int i = 0; i < NN / 4; ++i) {
            float4 xv = xr[i];
            float4 lv = *(const float4*)(xl + 4 * i);
            dg += xv.x * lv.x + xv.y * lv.y + xv.z * lv.z + xv.w * lv.w;
        }
        G[b1 * NN + b2] = dg;
    }
}

// ---- Kernel C: gs[c] = colsum of G
__global__ __launch_bounds__(256) void colsum_kernel(
    const float* __restrict__ G, float* __restrict__ gs)
{
    const int c = blockIdx.x * 256 + threadIdx.x;
    float s = 0.f;
    for (int bp = 0; bp < NN; ++bp) s += G[bp * NN + c];
    gs[c] = s;
}

// ---- Kernel D: quad table. tab[((idx*128)+q)*512 + c]
__global__ __launch_bounds__(256) void build_table_kernel(
    const float* __restrict__ G, float* __restrict__ tab)
{
    const int q = blockIdx.x;        // 0..127
    const int j = threadIdx.x;       // 0..255
    for (int c = j; c < NN; c += 256) {
        const float g0 = G[(4 * q + 0) * NN + c];
        const float g1 = G[(4 * q + 1) * NN + c];
        const float g2 = G[(4 * q + 2) * NN + c];
        const float g3 = G[(4 * q + 3) * NN + c];
#pragma unroll
        for (int idx = 0; idx < 16; ++idx) {
            float val = 0.f;
            if (idx & 1) val += g0;
            if (idx & 2) val += g1;
            if (idx & 4) val += g2;
            if (idx & 8) val += g3;
            tab[(((size_t)idx * 128 + q) << 9) + c] = val;
        }
    }
}

// ---- Main step kernel: 512 blocks (1 row) x 512 threads.
// h = tid>>7 in 0..3 handles quads 32h..32h+31; l = tid&127 handles cols 4l..4l+3.
// Partial accs reduced via LDS; v-state lives in h==0 threads.
// Spikes emitted as packed bits: sp[t][r][w], word w bit p <-> col 32w+p.
__global__ __launch_bounds__(512) void snn_quad3_kernel(
    const float* __restrict__ M, const float* __restrict__ tab,
    const float* __restrict__ V0, const float* __restrict__ gs,
    const float* __restrict__ alpha, const float* __restrict__ eta,
    const float* __restrict__ beta, unsigned* __restrict__ sp, int T)
{
    const int tid = threadIdx.x;
    const int l = tid & 127;
    const int h = tid >> 7;           // 0..3
    const int r = blockIdx.x;
    const int c0 = 4 * l;

    __shared__ float4 pacc[4][128];
    __shared__ unsigned char ib[128] __attribute__((aligned(16)));
    __shared__ unsigned char sb[128] __attribute__((aligned(16)));

    const float a = alpha[0], e = eta[0], bt = beta[0];
    const float kk = 0.2f;                    // dt / tao_u
    const float dd = 0.36787944117144233f;    // exp(-1)
    const float Vth = 0.2f;

    float4 v = make_float4(0.f, 0.f, 0.f, 0.f);
    float4 m = v, cg = v;
    if (h == 0) {
        v = *(const float4*)(V0 + (size_t)r * NN + c0);
        m = *(const float4*)(M + (size_t)r * NN + c0);
        const float4 g4 = *(const float4*)(gs + c0);
        cg.x = e * bt * g4.x; cg.y = e * bt * g4.y;
        cg.z = e * bt * g4.z; cg.w = e * bt * g4.w;
    }
    const float* tb = tab + c0;       // + idx*65536 + q*512
    float em = 1.0f;

    for (int t = 0; t < T; ++t) {
        if (h == 0) {
            float4 u;
            u.x = kk * fmaf(a, v.x, m.x * em);
            u.y = kk * fmaf(a, v.y, m.y * em);
            u.z = kk * fmaf(a, v.z, m.z * em);
            u.w = kk * fmaf(a, v.w, m.w * em);
            const unsigned hn = (u.x > 0.f ? 1u : 0u) | (u.y > 0.f ? 2u : 0u)
                              | (u.z > 0.f ? 4u : 0u) | (u.w > 0.f ? 8u : 0u);
            const unsigned sn = (u.x > Vth ? 1u : 0u) | (u.y > Vth ? 2u : 0u)
                              | (u.z > Vth ? 4u : 0u) | (u.w > Vth ? 8u : 0u);
            ib[l] = (unsigned char)hn;
            sb[l] = (unsigned char)sn;
        }
        __syncthreads();   // B1: ib/sb visible

        // table partial sums over this thread's 32 quads
        float4 acc = make_float4(0.f, 0.f, 0.f, 0.f);
        {
            const uint4 wa = ((const uint4*)ib)[2 * h];
            const uint4 wb = ((const uint4*)ib)[2 * h + 1];
            const unsigned wz[8] = {wa.x, wa.y, wa.z, wa.w, wb.x, wb.y, wb.z, wb.w};
#pragma unroll
            for (int d = 0; d < 8; ++d) {
                const unsigned w = wz[d];
#pragma unroll
                for (int k = 0; k < 4; ++k) {
                    const int q = 32 * h + 4 * d + k;
                    const unsigned ibyte = (w >> (8 * k)) & 0xFFu;
                    const float4 tv = *(const float4*)(tb + ((size_t)ibyte << 16) + (q << 9));
                    acc.x += tv.x; acc.y += tv.y; acc.z += tv.z; acc.w += tv.w;
                }
            }
        }
        pacc[h][l] = acc;

        // pack + emit this step's 512 spike bits (64B per block-step)
        if (tid < 16) {
            const uint2 b8 = ((const uint2*)sb)[tid];
            unsigned x = b8.x; x = (x | (x >> 4)) & 0x00FF00FFu; x = (x | (x >> 8)) & 0x0000FFFFu;
            unsigned y = b8.y; y = (y | (y >> 4)) & 0x00FF00FFu; y = (y | (y >> 8)) & 0x0000FFFFu;
            sp[((size_t)t * NN + r) * 16 + tid] = x | (y << 16);
        }
        __syncthreads();   // B2: pacc visible

        if (h == 0) {
            const float4 p0 = pacc[0][l];
            const float4 p1 = pacc[1][l];
            const float4 p2 = pacc[2][l];
            const float4 p3 = pacc[3][l];
            float4 s4;
            s4.x = ((p0.x + p1.x) + p2.x) + p3.x;
            s4.y = ((p0.y + p1.y) + p2.y) + p3.y;
            s4.z = ((p0.z + p1.z) + p2.z) + p3.z;
            s4.w = ((p0.w + p1.w) + p2.w) + p3.w;
            v.x = fmaf(dd, v.x, fmaf(e, s4.x, cg.x));
            v.y = fmaf(dd, v.y, fmaf(e, s4.y, cg.y));
            v.z = fmaf(dd, v.z, fmaf(e, s4.z, cg.z));
            v.w = fmaf(dd, v.w, fmaf(e, s4.w, cg.w));
        }
        em *= dd;
    }
}

// ---- Expand: out[t][b][o] = bit b of sp[t][o][b>>5]. Fully-coalesced f32 stores.
// grid = T*8 (t = bid>>3, btile = bid&7 covering b in [64*btile, 64*btile+64)).
__global__ __launch_bounds__(256) void expand_kernel(
    const unsigned* __restrict__ sp, float* __restrict__ out)
{
    const int tid = threadIdx.x;
    const int t = blockIdx.x >> 3;
    const int bt8 = blockIdx.x & 7;

    __shared__ uint2 sh[NN];          // words (2*bt8, 2*bt8+1) for each row o
    const uint2* spw = (const uint2*)sp;   // 8 uint2 per row
    sh[tid]       = spw[((size_t)t * NN + tid) * 8 + bt8];
    sh[tid + 256] = spw[((size_t)t * NN + tid + 256) * 8 + bt8];
    __syncthreads();

    const int b = bt8 * 64 + (tid >> 2);
    const int sub = tid & 3;
    const int rw = (tid >> 2) >> 5;   // which word of the pair
    const int bit = b & 31;
    float* op = out + (size_t)t * (NN * NN) + (size_t)b * NN;

#pragma unroll 4
    for (int i = 0; i < 32; ++i) {
        const int o = sub * 4 + i * 16;
        const uint2 w0 = sh[o];
        const uint2 w1 = sh[o + 1];
        const uint2 w2 = sh[o + 2];
        const uint2 w3 = sh[o + 3];
        float4 f;
        f.x = (float)(((rw ? w0.y : w0.x) >> bit) & 1u);
        f.y = (float)(((rw ? w1.y : w1.x) >> bit) & 1u);
        f.z = (float)(((rw ? w2.y : w2.x) >> bit) & 1u);
        f.w = (float)(((rw ? w3.y : w3.x) >> bit) & 1u);
        *(float4*)(op + o) = f;
    }
}

// ---- Fallback 1 (ws fits table but not sp): round-2 quad kernel, direct writes.
__global__ __launch_bounds__(128) void snn_quad_kernel(
    const float* __restrict__ M, const float* __restrict__ tab,
    const float* __restrict__ V0, const float* __restrict__ gs,
    const float* __restrict__ alpha, const float* __restrict__ eta,
    const float* __restrict__ beta, float* __restrict__ out, int T)
{
    const int l = threadIdx.x;
    const int r = blockIdx.x;
    const int c0 = 4 * l;
    const float a = alpha[0], e = eta[0], bt = beta[0];
    const float kk = 0.2f, dd = 0.36787944117144233f, Vth = 0.2f;

    float4 v = *(const float4*)(V0 + (size_t)r * NN + c0);
    const float4 m = *(const float4*)(M + (size_t)r * NN + c0);
    const float4 g4 = *(const float4*)(gs + c0);
    float4 cg;
    cg.x = e * bt * g4.x; cg.y = e * bt * g4.y;
    cg.z = e * bt * g4.z; cg.w = e * bt * g4.w;

    __shared__ uint4 idxq[2][8];
    const float* tb = tab + c0;
    float em = 1.0f;
    int p = 0;

    for (int t = 0; t < T; ++t) {
        float4 u;
        u.x = kk * fmaf(a, v.x, m.x * em);
        u.y = kk * fmaf(a, v.y, m.y * em);
        u.z = kk * fmaf(a, v.z, m.z * em);
        u.w = kk * fmaf(a, v.w, m.w * em);

        float* op = out + (size_t)t * (NN * NN) + (size_t)c0 * NN + r;
        op[0]      = u.x > Vth ? 1.f : 0.f;
        op[NN]     = u.y > Vth ? 1.f : 0.f;
        op[2 * NN] = u.z > Vth ? 1.f : 0.f;
        op[3 * NN] = u.w > Vth ? 1.f : 0.f;

        unsigned idx = (u.x > 0.f ? 1u : 0u) | (u.y > 0.f ? 2u : 0u)
                     | (u.z > 0.f ? 4u : 0u) | (u.w > 0.f ? 8u : 0u);
        ((unsigned char*)&idxq[p][0])[l] = (unsigned char)idx;
        __syncthreads();

        float4 acc = make_float4(0.f, 0.f, 0.f, 0.f);
#pragma unroll
        for (int g = 0; g < 4; ++g) {
            const uint4 wa = idxq[p][2 * g];
            const uint4 wb = idxq[p][2 * g + 1];
            const unsigned wz[8] = {wa.x, wa.y, wa.z, wa.w, wb.x, wb.y, wb.z, wb.w};
#pragma unroll
            for (int d = 0; d < 8; ++d) {
                const unsigned w = wz[d];
#pragma unroll
                for (int k = 0; k < 4; ++k) {
                    const int q = 32 * g + 4 * d + k;
                    const unsigned ibyt = (w >> (8 * k)) & 0xFFu;
                    const float4 tv = *(const float4*)(tb + ((size_t)ibyt << 16) + (q << 9));
                    acc.x += tv.x; acc.y += tv.y; acc.z += tv.z; acc.w += tv.w;
                }
            }
        }

        v.x = fmaf(dd, v.x, fmaf(e, acc.x, cg.x));
        v.y = fmaf(dd, v.y, fmaf(e, acc.y, cg.y));
        v.z = fmaf(dd, v.z, fmaf(e, acc.z, cg.z));
        v.w = fmaf(dd, v.w, fmaf(e, acc.w, cg.w));
        em *= dd;
        p ^= 1;
    }
}

// ---- Fallback 2 (tiny ws): round-1 kernel.
__global__ __launch_bounds__(256) void snn_step_kernel(
    const float* __restrict__ M, const float* __restrict__ G,
    const float* __restrict__ V0, const float* __restrict__ gs,
    const float* __restrict__ alpha, const float* __restrict__ eta,
    const float* __restrict__ beta, float* __restrict__ out, int T)
{
    const int j = threadIdx.x;
    const int r0 = blockIdx.x * 2;
    const int c0 = 2 * j;
    const float a = alpha[0], e = eta[0], bt = beta[0];
    const float kk = 0.2f, dd = 0.36787944117144233f, Vth = 0.2f;

    float v00 = V0[r0 * NN + c0];
    float v01 = V0[r0 * NN + c0 + 1];
    float v10 = V0[(r0 + 1) * NN + c0];
    float v11 = V0[(r0 + 1) * NN + c0 + 1];
    const float m00 = M[r0 * NN + c0];
    const float m01 = M[r0 * NN + c0 + 1];
    const float m10 = M[(r0 + 1) * NN + c0];
    const float m11 = M[(r0 + 1) * NN + c0 + 1];
    const float gs0 = gs[c0];
    const float gs1 = gs[c0 + 1];

    __shared__ float2 hp[NN];
    float em = 1.0f;
    const float2* Gcol = (const float2*)G + j;

    for (int t = 0; t < T; ++t) {
        const float u00 = kk * (m00 * em + a * v00);
        const float u01 = kk * (m01 * em + a * v01);
        const float u10 = kk * (m10 * em + a * v10);
        const float u11 = kk * (m11 * em + a * v11);

        float* outp = out + (size_t)t * (NN * NN);
        float2 sA = make_float2(u00 > Vth ? 1.f : 0.f, u10 > Vth ? 1.f : 0.f);
        float2 sB = make_float2(u01 > Vth ? 1.f : 0.f, u11 > Vth ? 1.f : 0.f);
        *(float2*)(outp + (size_t)c0 * NN + r0) = sA;
        *(float2*)(outp + (size_t)(c0 + 1) * NN + r0) = sB;

        hp[c0]     = make_float2(u00 > 0.f ? 1.f : 0.f, u10 > 0.f ? 1.f : 0.f);
        hp[c0 + 1] = make_float2(u01 > 0.f ? 1.f : 0.f, u11 > 0.f ? 1.f : 0.f);
        __syncthreads();

        float acc00 = 0.f, acc01 = 0.f, acc10 = 0.f, acc11 = 0.f;
#pragma unroll 8
        for (int bp = 0; bp < NN; ++bp) {
            float2 h = hp[bp];
            float2 g = Gcol[(size_t)bp * 256];
            acc00 = fmaf(h.x, g.x, acc00);
            acc01 = fmaf(h.x, g.y, acc01);
            acc10 = fmaf(h.y, g.x, acc10);
            acc11 = fmaf(h.y, g.y, acc11);
        }

        v00 = dd * v00 + e * (acc00 + bt * gs0);
        v01 = dd * v01 + e * (acc01 + bt * gs1);
        v10 = dd * v10 + e * (acc10 + bt * gs0);
        v11 = dd * v11 + e * (acc11 + bt * gs1);
        em *= dd;
        __syncthreads();
    }
}

extern "C" void kernel_launch(void* const* d_in, const int* in_sizes, int n_in,
                              void* d_out, int out_size, void* d_ws, size_t ws_size,
                              hipStream_t stream)
{
    const float* x     = (const float*)d_in[0];
    const float* W     = (const float*)d_in[1];
    const float* bias  = (const float*)d_in[2];
    const float* alpha = (const float*)d_in[3];
    const float* eta   = (const float*)d_in[4];
    const float* beta  = (const float*)d_in[5];
    const float* P0    = (const float*)d_in[6];
    (void)in_sizes; (void)n_in;

    const int T = out_size / (NN * NN);

    float* ws  = (float*)d_ws;
    float* M   = ws;                            // [512,512]
    float* G   = ws + NN * NN;                  // [512,512]
    float* V0  = ws + 2 * NN * NN;              // [512,512]
    float* gsv = ws + 3 * NN * NN;              // [512]
    float* tab = ws + 3 * NN * NN + NN;         // [16][128][512] = 4 MB
    unsigned* sp = (unsigned*)(tab + (size_t)16 * 128 * 512);  // [T][512][16] words

    const size_t need_tab = ((size_t)3 * NN * NN + NN + (size_t)16 * 128 * 512) * 4;
    const size_t need_sp  = need_tab + (size_t)T * NN * 16 * 4;

    hipLaunchKernelGGL(mlp_v0_kernel, dim3(NN), dim3(256), 0, stream, x, W, bias, P0, M, V0);
    hipLaunchKernelGGL(gram_kernel,   dim3(NN), dim3(256), 0, stream, x, G);
    hipLaunchKernelGGL(colsum_kernel, dim3(2),  dim3(256), 0, stream, G, gsv);

    if (ws_size >= need_sp) {
        hipLaunchKernelGGL(build_table_kernel, dim3(128), dim3(256), 0, stream, G, tab);
        hipLaunchKernelGGL(snn_quad3_kernel, dim3(NN), dim3(512), 0, stream,
                           M, tab, V0, gsv, alpha, eta, beta, sp, T);
        hipLaunchKernelGGL(expand_kernel, dim3(T * 8), dim3(256), 0, stream,
                           sp, (float*)d_out);
    } else if (ws_size >= need_tab) {
        hipLaunchKernelGGL(build_table_kernel, dim3(128), dim3(256), 0, stream, G, tab);
        hipLaunchKernelGGL(snn_quad_kernel, dim3(NN), dim3(128), 0, stream,
                           M, tab, V0, gsv, alpha, eta, beta, (float*)d_out, T);
    } else {
        hipLaunchKernelGGL(snn_step_kernel, dim3(256), dim3(256), 0, stream,
                           M, G, V0, gsv, alpha, eta, beta, (float*)d_out, T);
    }
}

// Round 4
// 182.845 us; speedup vs baseline: 5.9578x; 2.5326x over previous
//
#include <hip/hip_runtime.h>

// B = IN = OUT = 512; T from out_size.
// v_t = P_t @ x^T [OUT,B]; G = x@x^T [B,B]
//   u = k*(M*e^{-t} + a*v);  h = (u>0);  s = (u>0.2)
//   v' = d*v + e*(h@G + bt*colsum(G))
// h@G via quad table tab[idx][q][c] (16 x 128 x 512 f32 = 4 MB), maintained
// INCREMENTALLY: per step only quads whose 4-bit idx changed contribute
// tab[new]-tab[old]. Spike pattern freezes after ~10-15 steps (em decays e^-1,
// v converges at 0.368^t), so steady-state steps read ~nothing from L2.
// Full-recompute guard when >56 quads change keeps worst case ~= round-3 speed.

#define NN 512
#define KC 32

// ---- Tiled dual NT GEMM: D1[r,c] = sum_k A1[r,k]*B[c,k] (+bias, relu if bias)
//      D2[r,c] = sum_k A2[r,k]*B[c,k] (if A2 != null). 64x64 tiles, 256 thr, 4x4 micro.
__global__ __launch_bounds__(256) void dual_gemm_nt_kernel(
    const float* __restrict__ A1, const float* __restrict__ A2,
    const float* __restrict__ Bm, const float* __restrict__ bias,
    float* __restrict__ D1, float* __restrict__ D2)
{
    const int t = threadIdx.x;
    const int tx = t & 15, ty = t >> 4;
    const int rb = (blockIdx.x >> 3) << 6;
    const int cb = (blockIdx.x & 7) << 6;

    __shared__ float A1t[KC][68];   // 68: keeps 16B alignment of rows, spreads banks
    __shared__ float A2t[KC][68];
    __shared__ float Bt[KC][68];

    float acc1[4][4] = {{0.f}}, acc2[4][4] = {{0.f}};
    const bool dual = (A2 != nullptr);

    const int lr = t >> 2;           // 0..63 tile row
    const int lk = (t & 3) << 3;     // 0,8,16,24

    for (int k0 = 0; k0 < NN; k0 += KC) {
        const float4 a1a = *(const float4*)(A1 + (size_t)(rb + lr) * NN + k0 + lk);
        const float4 a1b = *(const float4*)(A1 + (size_t)(rb + lr) * NN + k0 + lk + 4);
        const float4 bva = *(const float4*)(Bm + (size_t)(cb + lr) * NN + k0 + lk);
        const float4 bvb = *(const float4*)(Bm + (size_t)(cb + lr) * NN + k0 + lk + 4);
        float4 a2a = make_float4(0.f, 0.f, 0.f, 0.f), a2b = a2a;
        if (dual) {
            a2a = *(const float4*)(A2 + (size_t)(rb + lr) * NN + k0 + lk);
            a2b = *(const float4*)(A2 + (size_t)(rb + lr) * NN + k0 + lk + 4);
        }
        __syncthreads();
        A1t[lk + 0][lr] = a1a.x; A1t[lk + 1][lr] = a1a.y; A1t[lk + 2][lr] = a1a.z; A1t[lk + 3][lr] = a1a.w;
        A1t[lk + 4][lr] = a1b.x; A1t[lk + 5][lr] = a1b.y; A1t[lk + 6][lr] = a1b.z; A1t[lk + 7][lr] = a1b.w;
        Bt[lk + 0][lr] = bva.x; Bt[lk + 1][lr] = bva.y; Bt[lk + 2][lr] = bva.z; Bt[lk + 3][lr] = bva.w;
        Bt[lk + 4][lr] = bvb.x; Bt[lk + 5][lr] = bvb.y; Bt[lk + 6][lr] = bvb.z; Bt[lk + 7][lr] = bvb.w;
        if (dual) {
            A2t[lk + 0][lr] = a2a.x; A2t[lk + 1][lr] = a2a.y; A2t[lk + 2][lr] = a2a.z; A2t[lk + 3][lr] = a2a.w;
            A2t[lk + 4][lr] = a2b.x; A2t[lk + 5][lr] = a2b.y; A2t[lk + 6][lr] = a2b.z; A2t[lk + 7][lr] = a2b.w;
        }
        __syncthreads();

#pragma unroll
        for (int k = 0; k < KC; ++k) {
            const float4 av4 = *(const float4*)&A1t[k][ty << 2];
            const float4 bv4 = *(const float4*)&Bt[k][tx << 2];
            const float av[4] = {av4.x, av4.y, av4.z, av4.w};
            const float bv[4] = {bv4.x, bv4.y, bv4.z, bv4.w};
#pragma unroll
            for (int i = 0; i < 4; ++i)
#pragma unroll
                for (int j = 0; j < 4; ++j)
                    acc1[i][j] = fmaf(av[i], bv[j], acc1[i][j]);
            if (dual) {
                const float4 cv4 = *(const float4*)&A2t[k][ty << 2];
                const float cv[4] = {cv4.x, cv4.y, cv4.z, cv4.w};
#pragma unroll
                for (int i = 0; i < 4; ++i)
#pragma unroll
                    for (int j = 0; j < 4; ++j)
                        acc2[i][j] = fmaf(cv[i], bv[j], acc2[i][j]);
            }
        }
    }

#pragma unroll
    for (int i = 0; i < 4; ++i) {
        const int r = rb + (ty << 2) + i;
        float4 o;
        o.x = acc1[i][0]; o.y = acc1[i][1]; o.z = acc1[i][2]; o.w = acc1[i][3];
        if (bias != nullptr) {
            const float bb = bias[r];
            o.x = fmaxf(o.x + bb, 0.f); o.y = fmaxf(o.y + bb, 0.f);
            o.z = fmaxf(o.z + bb, 0.f); o.w = fmaxf(o.w + bb, 0.f);
        }
        *(float4*)(D1 + (size_t)r * NN + cb + (tx << 2)) = o;
        if (dual) {
            float4 p;
            p.x = acc2[i][0]; p.y = acc2[i][1]; p.z = acc2[i][2]; p.w = acc2[i][3];
            *(float4*)(D2 + (size_t)r * NN + cb + (tx << 2)) = p;
        }
    }
}

// ---- colsum: 8 blocks x 256 thr; block covers 64 cols, 4-way row split + LDS reduce
__global__ __launch_bounds__(256) void colsum_kernel(
    const float* __restrict__ G, float* __restrict__ gs)
{
    __shared__ float red[4][64];
    const int tid = threadIdx.x;
    const int c = (blockIdx.x << 6) + (tid & 63);
    const int g = tid >> 6;
    float s = 0.f;
    for (int bp = 128 * g; bp < 128 * g + 128; ++bp) s += G[(size_t)bp * NN + c];
    if (g > 0) red[g][tid & 63] = s;
    __syncthreads();
    if (g == 0) gs[c] = ((s + red[1][tid & 63]) + red[2][tid & 63]) + red[3][tid & 63];
}

// ---- quad table: tab[((idx*128)+q)*512 + c]
__global__ __launch_bounds__(256) void build_table_kernel(
    const float* __restrict__ G, float* __restrict__ tab)
{
    const int q = blockIdx.x;
    const int j = threadIdx.x;
    for (int c = j; c < NN; c += 256) {
        const float g0 = G[(4 * q + 0) * NN + c];
        const float g1 = G[(4 * q + 1) * NN + c];
        const float g2 = G[(4 * q + 2) * NN + c];
        const float g3 = G[(4 * q + 3) * NN + c];
#pragma unroll
        for (int idx = 0; idx < 16; ++idx) {
            float val = 0.f;
            if (idx & 1) val += g0;
            if (idx & 2) val += g1;
            if (idx & 4) val += g2;
            if (idx & 8) val += g3;
            tab[(((size_t)idx * 128 + q) << 9) + c] = val;
        }
    }
}

// ---- Main delta step kernel: 512 blocks (1 row) x 512 threads.
// h = tid>>7 group, l = tid&127 (cols 4l..4l+3 = quad l for the h==0 group).
// Persistent per-thread partial accp; per step only changed quads read table.
__global__ __launch_bounds__(512) void snn_delta_kernel(
    const float* __restrict__ M, const float* __restrict__ tab,
    const float* __restrict__ V0, const float* __restrict__ gs,
    const float* __restrict__ alpha, const float* __restrict__ eta,
    const float* __restrict__ beta, unsigned* __restrict__ sp, int T)
{
    const int tid = threadIdx.x;
    const int l = tid & 127;
    const int h = tid >> 7;
    const int r = blockIdx.x;
    const int c0 = 4 * l;

    __shared__ float4 pacc[4][128];
    __shared__ unsigned char ib[128] __attribute__((aligned(16)));
    __shared__ unsigned char sb[128] __attribute__((aligned(16)));
    __shared__ unsigned short list[128];
    __shared__ unsigned cnts[2];

    const float a = alpha[0], e = eta[0], bt = beta[0];
    const float kk = 0.2f;
    const float dd = 0.36787944117144233f;
    const float Vth = 0.2f;

    float4 v = make_float4(0.f, 0.f, 0.f, 0.f);
    float4 m = v, cg = v;
    if (h == 0) {
        v = *(const float4*)(V0 + (size_t)r * NN + c0);
        m = *(const float4*)(M + (size_t)r * NN + c0);
        const float4 g4 = *(const float4*)(gs + c0);
        cg.x = e * bt * g4.x; cg.y = e * bt * g4.y;
        cg.z = e * bt * g4.z; cg.w = e * bt * g4.w;
    }
    const float* tb = tab + c0;
    float4 accp = make_float4(0.f, 0.f, 0.f, 0.f);
    unsigned oldidx = 0;              // tab[0][q] == 0, so "from zero" is exact
    float em = 1.0f;

    for (int t = 0; t < T; ++t) {
        if (h == 0) {
            float4 u;
            u.x = kk * fmaf(a, v.x, m.x * em);
            u.y = kk * fmaf(a, v.y, m.y * em);
            u.z = kk * fmaf(a, v.z, m.z * em);
            u.w = kk * fmaf(a, v.w, m.w * em);
            const unsigned hn = (u.x > 0.f ? 1u : 0u) | (u.y > 0.f ? 2u : 0u)
                              | (u.z > 0.f ? 4u : 0u) | (u.w > 0.f ? 8u : 0u);
            const unsigned sn = (u.x > Vth ? 1u : 0u) | (u.y > Vth ? 2u : 0u)
                              | (u.z > Vth ? 4u : 0u) | (u.w > Vth ? 8u : 0u);
            ib[l] = (unsigned char)hn;
            sb[l] = (unsigned char)sn;
            const bool changed = (hn != oldidx);
            const unsigned long long mask = __ballot(changed);
            const int lane = tid & 63;
            const int pos = (int)__popcll(mask & ((1ull << lane) - 1ull));
            if (changed) {
                const int base = (tid < 64) ? 0 : 64;
                list[base + pos] = (unsigned short)(l | (oldidx << 7) | (hn << 11));
            }
            if (lane == 0) cnts[tid >> 6] = (unsigned)__popcll(mask);
            oldidx = hn;
        }
        __syncthreads();   // B1: ib/sb/list/cnts visible

        // pack + emit this step's 512 spike bits (64B per block-step)
        if (tid < 16) {
            const uint2 b8 = ((const uint2*)sb)[tid];
            unsigned x = b8.x; x = (x | (x >> 4)) & 0x00FF00FFu; x = (x | (x >> 8)) & 0x0000FFFFu;
            unsigned y = b8.y; y = (y | (y >> 4)) & 0x00FF00FFu; y = (y | (y >> 8)) & 0x0000FFFFu;
            sp[((size_t)t * NN + r) * 16 + tid] = x | (y << 16);
        }

        const int n0 = (int)cnts[0];
        const int n1 = (int)cnts[1];
        const int n = n0 + n1;

        if (n > 56) {
            // full recompute of this h-group's 32-quad partial (resets telescoping)
            float4 acc = make_float4(0.f, 0.f, 0.f, 0.f);
            const uint4 wa = ((const uint4*)ib)[2 * h];
            const uint4 wb = ((const uint4*)ib)[2 * h + 1];
            const unsigned wz[8] = {wa.x, wa.y, wa.z, wa.w, wb.x, wb.y, wb.z, wb.w};
#pragma unroll
            for (int d = 0; d < 8; ++d) {
                const unsigned w = wz[d];
#pragma unroll
                for (int k = 0; k < 4; ++k) {
                    const int q = 32 * h + 4 * d + k;
                    const unsigned ibyte = (w >> (8 * k)) & 0xFFu;
                    const float4 tv = *(const float4*)(tb + ((size_t)ibyte << 16) + (q << 9));
                    acc.x += tv.x; acc.y += tv.y; acc.z += tv.z; acc.w += tv.w;
                }
            }
            accp = acc;
        } else {
            for (int j = h; j < n; j += 4) {
                const int lj = (j < n0) ? j : 64 + (j - n0);
                const unsigned ent = list[lj];
                const int q = ent & 127;
                const unsigned oldi = (ent >> 7) & 15u;
                const unsigned newi = (ent >> 11) & 15u;
                const float4 tn = *(const float4*)(tb + ((size_t)newi << 16) + (q << 9));
                const float4 to = *(const float4*)(tb + ((size_t)oldi << 16) + (q << 9));
                accp.x += tn.x - to.x; accp.y += tn.y - to.y;
                accp.z += tn.z - to.z; accp.w += tn.w - to.w;
            }
        }
        pacc[h][l] = accp;
        __syncthreads();   // B2: pacc visible

        if (h == 0) {
            const float4 p0 = pacc[0][l];
            const float4 p1 = pacc[1][l];
            const float4 p2 = pacc[2][l];
            const float4 p3 = pacc[3][l];
            float4 s4;
            s4.x = ((p0.x + p1.x) + p2.x) + p3.x;
            s4.y = ((p0.y + p1.y) + p2.y) + p3.y;
            s4.z = ((p0.z + p1.z) + p2.z) + p3.z;
            s4.w = ((p0.w + p1.w) + p2.w) + p3.w;
            v.x = fmaf(dd, v.x, fmaf(e, s4.x, cg.x));
            v.y = fmaf(dd, v.y, fmaf(e, s4.y, cg.y));
            v.z = fmaf(dd, v.z, fmaf(e, s4.z, cg.z));
            v.w = fmaf(dd, v.w, fmaf(e, s4.w, cg.w));
        }
        em *= dd;
    }
}

// ---- Expand: out[t][b][o] = bit b of sp[t][o][b>>5]. Coalesced float4 stores.
__global__ __launch_bounds__(256) void expand_kernel(
    const unsigned* __restrict__ sp, float* __restrict__ out)
{
    const int tid = threadIdx.x;
    const int t = blockIdx.x >> 3;
    const int bt8 = blockIdx.x & 7;

    __shared__ uint2 sh[NN];
    const uint2* spw = (const uint2*)sp;
    sh[tid]       = spw[((size_t)t * NN + tid) * 8 + bt8];
    sh[tid + 256] = spw[((size_t)t * NN + tid + 256) * 8 + bt8];
    __syncthreads();

    const int b = bt8 * 64 + (tid >> 2);
    const int sub = tid & 3;
    const int rw = (tid >> 2) >> 5;
    const int bit = b & 31;
    float* op = out + (size_t)t * (NN * NN) + (size_t)b * NN;

#pragma unroll 4
    for (int i = 0; i < 32; ++i) {
        const int o = sub * 4 + i * 16;
        const uint2 w0 = sh[o];
        const uint2 w1 = sh[o + 1];
        const uint2 w2 = sh[o + 2];
        const uint2 w3 = sh[o + 3];
        float4 f;
        f.x = (float)(((rw ? w0.y : w0.x) >> bit) & 1u);
        f.y = (float)(((rw ? w1.y : w1.x) >> bit) & 1u);
        f.z = (float)(((rw ? w2.y : w2.x) >> bit) & 1u);
        f.w = (float)(((rw ? w3.y : w3.x) >> bit) & 1u);
        *(float4*)(op + o) = f;
    }
}

// ---- Fallback 1 (ws fits table but not sp): round-2 quad kernel, direct writes.
__global__ __launch_bounds__(128) void snn_quad_kernel(
    const float* __restrict__ M, const float* __restrict__ tab,
    const float* __restrict__ V0, const float* __restrict__ gs,
    const float* __restrict__ alpha, const float* __restrict__ eta,
    const float* __restrict__ beta, float* __restrict__ out, int T)
{
    const int l = threadIdx.x;
    const int r = blockIdx.x;
    const int c0 = 4 * l;
    const float a = alpha[0], e = eta[0], bt = beta[0];
    const float kk = 0.2f, dd = 0.36787944117144233f, Vth = 0.2f;

    float4 v = *(const float4*)(V0 + (size_t)r * NN + c0);
    const float4 m = *(const float4*)(M + (size_t)r * NN + c0);
    const float4 g4 = *(const float4*)(gs + c0);
    float4 cg;
    cg.x = e * bt * g4.x; cg.y = e * bt * g4.y;
    cg.z = e * bt * g4.z; cg.w = e * bt * g4.w;

    __shared__ uint4 idxq[2][8];
    const float* tb = tab + c0;
    float em = 1.0f;
    int p = 0;

    for (int t = 0; t < T; ++t) {
        float4 u;
        u.x = kk * fmaf(a, v.x, m.x * em);
        u.y = kk * fmaf(a, v.y, m.y * em);
        u.z = kk * fmaf(a, v.z, m.z * em);
        u.w = kk * fmaf(a, v.w, m.w * em);

        float* op = out + (size_t)t * (NN * NN) + (size_t)c0 * NN + r;
        op[0]      = u.x > Vth ? 1.f : 0.f;
        op[NN]     = u.y > Vth ? 1.f : 0.f;
        op[2 * NN] = u.z > Vth ? 1.f : 0.f;
        op[3 * NN] = u.w > Vth ? 1.f : 0.f;

        unsigned idx = (u.x > 0.f ? 1u : 0u) | (u.y > 0.f ? 2u : 0u)
                     | (u.z > 0.f ? 4u : 0u) | (u.w > 0.f ? 8u : 0u);
        ((unsigned char*)&idxq[p][0])[l] = (unsigned char)idx;
        __syncthreads();

        float4 acc = make_float4(0.f, 0.f, 0.f, 0.f);
#pragma unroll
        for (int g = 0; g < 4; ++g) {
            const uint4 wa = idxq[p][2 * g];
            const uint4 wb = idxq[p][2 * g + 1];
            const unsigned wz[8] = {wa.x, wa.y, wa.z, wa.w, wb.x, wb.y, wb.z, wb.w};
#pragma unroll
            for (int d = 0; d < 8; ++d) {
                const unsigned w = wz[d];
#pragma unroll
                for (int k = 0; k < 4; ++k) {
                    const int q = 32 * g + 4 * d + k;
                    const unsigned ibyt = (w >> (8 * k)) & 0xFFu;
                    const float4 tv = *(const float4*)(tb + ((size_t)ibyt << 16) + (q << 9));
                    acc.x += tv.x; acc.y += tv.y; acc.z += tv.z; acc.w += tv.w;
                }
            }
        }

        v.x = fmaf(dd, v.x, fmaf(e, acc.x, cg.x));
        v.y = fmaf(dd, v.y, fmaf(e, acc.y, cg.y));
        v.z = fmaf(dd, v.z, fmaf(e, acc.z, cg.z));
        v.w = fmaf(dd, v.w, fmaf(e, acc.w, cg.w));
        em *= dd;
        p ^= 1;
    }
}

// ---- Fallback 2 (tiny ws): round-1 kernel.
__global__ __launch_bounds__(256) void snn_step_kernel(
    const float* __restrict__ M, const float* __restrict__ G,
    const float* __restrict__ V0, const float* __restrict__ gs,
    const float* __restrict__ alpha, const float* __restrict__ eta,
    const float* __restrict__ beta, float* __restrict__ out, int T)
{
    const int j = threadIdx.x;
    const int r0 = blockIdx.x * 2;
    const int c0 = 2 * j;
    const float a = alpha[0], e = eta[0], bt = beta[0];
    const float kk = 0.2f, dd = 0.36787944117144233f, Vth = 0.2f;

    float v00 = V0[r0 * NN + c0];
    float v01 = V0[r0 * NN + c0 + 1];
    float v10 = V0[(r0 + 1) * NN + c0];
    float v11 = V0[(r0 + 1) * NN + c0 + 1];
    const float m00 = M[r0 * NN + c0];
    const float m01 = M[r0 * NN + c0 + 1];
    const float m10 = M[(r0 + 1) * NN + c0];
    const float m11 = M[(r0 + 1) * NN + c0 + 1];
    const float gs0 = gs[c0];
    const float gs1 = gs[c0 + 1];

    __shared__ float2 hp[NN];
    float em = 1.0f;
    const float2* Gcol = (const float2*)G + j;

    for (int t = 0; t < T; ++t) {
        const float u00 = kk * (m00 * em + a * v00);
        const float u01 = kk * (m01 * em + a * v01);
        const float u10 = kk * (m10 * em + a * v10);
        const float u11 = kk * (m11 * em + a * v11);

        float* outp = out + (size_t)t * (NN * NN);
        float2 sA = make_float2(u00 > Vth ? 1.f : 0.f, u10 > Vth ? 1.f : 0.f);
        float2 sB = make_float2(u01 > Vth ? 1.f : 0.f, u11 > Vth ? 1.f : 0.f);
        *(float2*)(outp + (size_t)c0 * NN + r0) = sA;
        *(float2*)(outp + (size_t)(c0 + 1) * NN + r0) = sB;

        hp[c0]     = make_float2(u00 > 0.f ? 1.f : 0.f, u10 > 0.f ? 1.f : 0.f);
        hp[c0 + 1] = make_float2(u01 > 0.f ? 1.f : 0.f, u11 > 0.f ? 1.f : 0.f);
        __syncthreads();

        float acc00 = 0.f, acc01 = 0.f, acc10 = 0.f, acc11 = 0.f;
#pragma unroll 8
        for (int bp = 0; bp < NN; ++bp) {
            float2 h = hp[bp];
            float2 g = Gcol[(size_t)bp * 256];
            acc00 = fmaf(h.x, g.x, acc00);
            acc01 = fmaf(h.x, g.y, acc01);
            acc10 = fmaf(h.y, g.x, acc10);
            acc11 = fmaf(h.y, g.y, acc11);
        }

        v00 = dd * v00 + e * (acc00 + bt * gs0);
        v01 = dd * v01 + e * (acc01 + bt * gs1);
        v10 = dd * v10 + e * (acc10 + bt * gs0);
        v11 = dd * v11 + e * (acc11 + bt * gs1);
        em *= dd;
        __syncthreads();
    }
}

extern "C" void kernel_launch(void* const* d_in, const int* in_sizes, int n_in,
                              void* d_out, int out_size, void* d_ws, size_t ws_size,
                              hipStream_t stream)
{
    const float* x     = (const float*)d_in[0];
    const float* W     = (const float*)d_in[1];
    const float* bias  = (const float*)d_in[2];
    const float* alpha = (const float*)d_in[3];
    const float* eta   = (const float*)d_in[4];
    const float* beta  = (const float*)d_in[5];
    const float* P0    = (const float*)d_in[6];
    (void)in_sizes; (void)n_in;

    const int T = out_size / (NN * NN);

    float* ws  = (float*)d_ws;
    float* M   = ws;                            // [512,512]
    float* G   = ws + NN * NN;                  // [512,512]
    float* V0  = ws + 2 * NN * NN;              // [512,512]
    float* gsv = ws + 3 * NN * NN;              // [512]
    float* tab = ws + 3 * NN * NN + NN;         // [16][128][512] = 4 MB
    unsigned* sp = (unsigned*)(tab + (size_t)16 * 128 * 512);  // [T][512][16]

    const size_t need_tab = ((size_t)3 * NN * NN + NN + (size_t)16 * 128 * 512) * 4;
    const size_t need_sp  = need_tab + (size_t)T * NN * 16 * 4;

    // prologue: M,V0 in one dual pass; G in a second; colsum
    hipLaunchKernelGGL(dual_gemm_nt_kernel, dim3(64), dim3(256), 0, stream,
                       W, P0, x, bias, M, V0);
    hipLaunchKernelGGL(dual_gemm_nt_kernel, dim3(64), dim3(256), 0, stream,
                       x, (const float*)nullptr, x, (const float*)nullptr, G, (float*)nullptr);
    hipLaunchKernelGGL(colsum_kernel, dim3(8), dim3(256), 0, stream, G, gsv);

    if (ws_size >= need_sp) {
        hipLaunchKernelGGL(build_table_kernel, dim3(128), dim3(256), 0, stream, G, tab);
        hipLaunchKernelGGL(snn_delta_kernel, dim3(NN), dim3(512), 0, stream,
                           M, tab, V0, gsv, alpha, eta, beta, sp, T);
        hipLaunchKernelGGL(expand_kernel, dim3(T * 8), dim3(256), 0, stream,
                           sp, (float*)d_out);
    } else if (ws_size >= need_tab) {
        hipLaunchKernelGGL(build_table_kernel, dim3(128), dim3(256), 0, stream, G, tab);
        hipLaunchKernelGGL(snn_quad_kernel, dim3(NN), dim3(128), 0, stream,
                           M, tab, V0, gsv, alpha, eta, beta, (float*)d_out, T);
    } else {
        hipLaunchKernelGGL(snn_step_kernel, dim3(256), dim3(256), 0, stream,
                           M, G, V0, gsv, alpha, eta, beta, (float*)d_out, T);
    }
}

// Round 5
// 152.388 us; speedup vs baseline: 7.1486x; 1.1999x over previous
//
#include <hip/hip_runtime.h>

// B = IN = OUT = 512; T from out_size.
// v_t = P_t @ x^T [OUT,B]; G = x@x^T [B,B]
//   u = k*(M*e^{-t} + a*v);  h = (u>0);  s = (u>0.2)
//   v' = d*v + e*(h@G + bt*colsum(G))
// h@G via quad table tab[idx][q][c] (16 x 128 x 512 f32 = 4 MB), maintained
// incrementally (only changed quads touch the table; spike pattern freezes
// after ~10 steps). Spikes packed to bits, expanded by a coalesced kernel.
// Round-5: prologue GEMMs reshaped to 32x32 tiles / grid 256 (1 block/CU)
// to fix the 2.5%-occupancy latency-bound 64-tile GEMM (58us -> ~7us).

#define NN 512
#define KC 32

// ---- 32x32-tile NT GEMM, optionally dual-A:
//  D1[r,c] = sum_k A1[r,k]*Bm[c,k] (+bias, relu if bias != null)
//  D2[r,c] = sum_k A2[r,k]*Bm[c,k] (if A2 != null)
// grid 256 (16x16 tiles), 256 threads, 2x2 micro-tile.
__global__ __launch_bounds__(256) void gemm32_nt_kernel(
    const float* __restrict__ A1, const float* __restrict__ A2,
    const float* __restrict__ Bm, const float* __restrict__ bias,
    float* __restrict__ D1, float* __restrict__ D2)
{
    const int tid = threadIdx.x;
    const int tx = tid & 15;          // cols 2tx, 2tx+1
    const int ty = tid >> 4;          // rows 2ty, 2ty+1
    const int rb = (blockIdx.x >> 4) << 5;
    const int cb = (blockIdx.x & 15) << 5;

    __shared__ float A1t[KC][36];     // [k][row]; 36: k*36 even -> 8B-aligned float2
    __shared__ float A2t[KC][36];
    __shared__ float Bt[KC][36];

    const bool dual = (A2 != nullptr);
    float acc1[2][2] = {{0.f, 0.f}, {0.f, 0.f}};
    float acc2[2][2] = {{0.f, 0.f}, {0.f, 0.f}};

    const int lrow = tid >> 3;        // 0..31
    const int lk = (tid & 7) << 2;    // 0,4,...,28

    for (int k0 = 0; k0 < NN; k0 += KC) {
        const float4 a1 = *(const float4*)(A1 + (size_t)(rb + lrow) * NN + k0 + lk);
        const float4 bv = *(const float4*)(Bm + (size_t)(cb + lrow) * NN + k0 + lk);
        float4 a2 = make_float4(0.f, 0.f, 0.f, 0.f);
        if (dual) a2 = *(const float4*)(A2 + (size_t)(rb + lrow) * NN + k0 + lk);
        __syncthreads();
        A1t[lk + 0][lrow] = a1.x; A1t[lk + 1][lrow] = a1.y;
        A1t[lk + 2][lrow] = a1.z; A1t[lk + 3][lrow] = a1.w;
        Bt[lk + 0][lrow] = bv.x; Bt[lk + 1][lrow] = bv.y;
        Bt[lk + 2][lrow] = bv.z; Bt[lk + 3][lrow] = bv.w;
        if (dual) {
            A2t[lk + 0][lrow] = a2.x; A2t[lk + 1][lrow] = a2.y;
            A2t[lk + 2][lrow] = a2.z; A2t[lk + 3][lrow] = a2.w;
        }
        __syncthreads();

#pragma unroll
        for (int k = 0; k < KC; ++k) {
            const float2 av = *(const float2*)&A1t[k][2 * ty];
            const float2 bw = *(const float2*)&Bt[k][2 * tx];
            acc1[0][0] = fmaf(av.x, bw.x, acc1[0][0]);
            acc1[0][1] = fmaf(av.x, bw.y, acc1[0][1]);
            acc1[1][0] = fmaf(av.y, bw.x, acc1[1][0]);
            acc1[1][1] = fmaf(av.y, bw.y, acc1[1][1]);
            if (dual) {
                const float2 cv = *(const float2*)&A2t[k][2 * ty];
                acc2[0][0] = fmaf(cv.x, bw.x, acc2[0][0]);
                acc2[0][1] = fmaf(cv.x, bw.y, acc2[0][1]);
                acc2[1][0] = fmaf(cv.y, bw.x, acc2[1][0]);
                acc2[1][1] = fmaf(cv.y, bw.y, acc2[1][1]);
            }
        }
    }

#pragma unroll
    for (int i = 0; i < 2; ++i) {
        const int r = rb + 2 * ty + i;
        float2 o = make_float2(acc1[i][0], acc1[i][1]);
        if (bias != nullptr) {
            const float bb = bias[r];
            o.x = fmaxf(o.x + bb, 0.f);
            o.y = fmaxf(o.y + bb, 0.f);
        }
        *(float2*)(D1 + (size_t)r * NN + cb + 2 * tx) = o;
        if (dual) {
            *(float2*)(D2 + (size_t)r * NN + cb + 2 * tx) = make_float2(acc2[i][0], acc2[i][1]);
        }
    }
}

// ---- colsum: 8 blocks x 256 thr; block covers 64 cols, 4-way row split + LDS reduce
__global__ __launch_bounds__(256) void colsum_kernel(
    const float* __restrict__ G, float* __restrict__ gs)
{
    __shared__ float red[4][64];
    const int tid = threadIdx.x;
    const int c = (blockIdx.x << 6) + (tid & 63);
    const int g = tid >> 6;
    float s = 0.f;
    for (int bp = 128 * g; bp < 128 * g + 128; ++bp) s += G[(size_t)bp * NN + c];
    if (g > 0) red[g][tid & 63] = s;
    __syncthreads();
    if (g == 0) gs[c] = ((s + red[1][tid & 63]) + red[2][tid & 63]) + red[3][tid & 63];
}

// ---- quad table: tab[((idx*128)+q)*512 + c]
__global__ __launch_bounds__(256) void build_table_kernel(
    const float* __restrict__ G, float* __restrict__ tab)
{
    const int q = blockIdx.x;
    const int j = threadIdx.x;
    for (int c = j; c < NN; c += 256) {
        const float g0 = G[(4 * q + 0) * NN + c];
        const float g1 = G[(4 * q + 1) * NN + c];
        const float g2 = G[(4 * q + 2) * NN + c];
        const float g3 = G[(4 * q + 3) * NN + c];
#pragma unroll
        for (int idx = 0; idx < 16; ++idx) {
            float val = 0.f;
            if (idx & 1) val += g0;
            if (idx & 2) val += g1;
            if (idx & 4) val += g2;
            if (idx & 8) val += g3;
            tab[(((size_t)idx * 128 + q) << 9) + c] = val;
        }
    }
}

// ---- Main delta step kernel: 512 blocks (1 row) x 512 threads.
// h = tid>>7 group, l = tid&127 (cols 4l..4l+3 = quad l for the h==0 group).
// Persistent per-thread partial accp; per step only changed quads read table.
__global__ __launch_bounds__(512) void snn_delta_kernel(
    const float* __restrict__ M, const float* __restrict__ tab,
    const float* __restrict__ V0, const float* __restrict__ gs,
    const float* __restrict__ alpha, const float* __restrict__ eta,
    const float* __restrict__ beta, unsigned* __restrict__ sp, int T)
{
    const int tid = threadIdx.x;
    const int l = tid & 127;
    const int h = tid >> 7;
    const int r = blockIdx.x;
    const int c0 = 4 * l;

    __shared__ float4 pacc[4][128];
    __shared__ unsigned char ib[128] __attribute__((aligned(16)));
    __shared__ unsigned char sb[128] __attribute__((aligned(16)));
    __shared__ unsigned short list[128];
    __shared__ unsigned cnts[2];

    const float a = alpha[0], e = eta[0], bt = beta[0];
    const float kk = 0.2f;
    const float dd = 0.36787944117144233f;
    const float Vth = 0.2f;

    float4 v = make_float4(0.f, 0.f, 0.f, 0.f);
    float4 m = v, cg = v;
    if (h == 0) {
        v = *(const float4*)(V0 + (size_t)r * NN + c0);
        m = *(const float4*)(M + (size_t)r * NN + c0);
        const float4 g4 = *(const float4*)(gs + c0);
        cg.x = e * bt * g4.x; cg.y = e * bt * g4.y;
        cg.z = e * bt * g4.z; cg.w = e * bt * g4.w;
    }
    const float* tb = tab + c0;
    float4 accp = make_float4(0.f, 0.f, 0.f, 0.f);
    unsigned oldidx = 0;              // tab[0][q] == 0, so "from zero" is exact
    float em = 1.0f;

    for (int t = 0; t < T; ++t) {
        if (h == 0) {
            float4 u;
            u.x = kk * fmaf(a, v.x, m.x * em);
            u.y = kk * fmaf(a, v.y, m.y * em);
            u.z = kk * fmaf(a, v.z, m.z * em);
            u.w = kk * fmaf(a, v.w, m.w * em);
            const unsigned hn = (u.x > 0.f ? 1u : 0u) | (u.y > 0.f ? 2u : 0u)
                              | (u.z > 0.f ? 4u : 0u) | (u.w > 0.f ? 8u : 0u);
            const unsigned sn = (u.x > Vth ? 1u : 0u) | (u.y > Vth ? 2u : 0u)
                              | (u.z > Vth ? 4u : 0u) | (u.w > Vth ? 8u : 0u);
            ib[l] = (unsigned char)hn;
            sb[l] = (unsigned char)sn;
            const bool changed = (hn != oldidx);
            const unsigned long long mask = __ballot(changed);
            const int lane = tid & 63;
            const int pos = (int)__popcll(mask & ((1ull << lane) - 1ull));
            if (changed) {
                const int base = (tid < 64) ? 0 : 64;
                list[base + pos] = (unsigned short)(l | (oldidx << 7) | (hn << 11));
            }
            if (lane == 0) cnts[tid >> 6] = (unsigned)__popcll(mask);
            oldidx = hn;
        }
        __syncthreads();   // B1: ib/sb/list/cnts visible

        // pack + emit this step's 512 spike bits (64B per block-step)
        if (tid < 16) {
            const uint2 b8 = ((const uint2*)sb)[tid];
            unsigned x = b8.x; x = (x | (x >> 4)) & 0x00FF00FFu; x = (x | (x >> 8)) & 0x0000FFFFu;
            unsigned y = b8.y; y = (y | (y >> 4)) & 0x00FF00FFu; y = (y | (y >> 8)) & 0x0000FFFFu;
            sp[((size_t)t * NN + r) * 16 + tid] = x | (y << 16);
        }

        const int n0 = (int)cnts[0];
        const int n1 = (int)cnts[1];
        const int n = n0 + n1;

        if (n > 56) {
            // full recompute of this h-group's 32-quad partial (resets telescoping)
            float4 acc = make_float4(0.f, 0.f, 0.f, 0.f);
            const uint4 wa = ((const uint4*)ib)[2 * h];
            const uint4 wb = ((const uint4*)ib)[2 * h + 1];
            const unsigned wz[8] = {wa.x, wa.y, wa.z, wa.w, wb.x, wb.y, wb.z, wb.w};
#pragma unroll
            for (int d = 0; d < 8; ++d) {
                const unsigned w = wz[d];
#pragma unroll
                for (int k = 0; k < 4; ++k) {
                    const int q = 32 * h + 4 * d + k;
                    const unsigned ibyte = (w >> (8 * k)) & 0xFFu;
                    const float4 tv = *(const float4*)(tb + ((size_t)ibyte << 16) + (q << 9));
                    acc.x += tv.x; acc.y += tv.y; acc.z += tv.z; acc.w += tv.w;
                }
            }
            accp = acc;
        } else {
            for (int j = h; j < n; j += 4) {
                const int lj = (j < n0) ? j : 64 + (j - n0);
                const unsigned ent = list[lj];
                const int q = ent & 127;
                const unsigned oldi = (ent >> 7) & 15u;
                const unsigned newi = (ent >> 11) & 15u;
                const float4 tn = *(const float4*)(tb + ((size_t)newi << 16) + (q << 9));
                const float4 to = *(const float4*)(tb + ((size_t)oldi << 16) + (q << 9));
                accp.x += tn.x - to.x; accp.y += tn.y - to.y;
                accp.z += tn.z - to.z; accp.w += tn.w - to.w;
            }
        }
        pacc[h][l] = accp;
        __syncthreads();   // B2: pacc visible

        if (h == 0) {
            const float4 p0 = pacc[0][l];
            const float4 p1 = pacc[1][l];
            const float4 p2 = pacc[2][l];
            const float4 p3 = pacc[3][l];
            float4 s4;
            s4.x = ((p0.x + p1.x) + p2.x) + p3.x;
            s4.y = ((p0.y + p1.y) + p2.y) + p3.y;
            s4.z = ((p0.z + p1.z) + p2.z) + p3.z;
            s4.w = ((p0.w + p1.w) + p2.w) + p3.w;
            v.x = fmaf(dd, v.x, fmaf(e, s4.x, cg.x));
            v.y = fmaf(dd, v.y, fmaf(e, s4.y, cg.y));
            v.z = fmaf(dd, v.z, fmaf(e, s4.z, cg.z));
            v.w = fmaf(dd, v.w, fmaf(e, s4.w, cg.w));
        }
        em *= dd;
    }
}

// ---- Expand: out[t][b][o] = bit b of sp[t][o][b>>5]. Coalesced float4 stores.
__global__ __launch_bounds__(256) void expand_kernel(
    const unsigned* __restrict__ sp, float* __restrict__ out)
{
    const int tid = threadIdx.x;
    const int t = blockIdx.x >> 3;
    const int bt8 = blockIdx.x & 7;

    __shared__ uint2 sh[NN];
    const uint2* spw = (const uint2*)sp;
    sh[tid]       = spw[((size_t)t * NN + tid) * 8 + bt8];
    sh[tid + 256] = spw[((size_t)t * NN + tid + 256) * 8 + bt8];
    __syncthreads();

    const int b = bt8 * 64 + (tid >> 2);
    const int sub = tid & 3;
    const int rw = (tid >> 2) >> 5;
    const int bit = b & 31;
    float* op = out + (size_t)t * (NN * NN) + (size_t)b * NN;

#pragma unroll 4
    for (int i = 0; i < 32; ++i) {
        const int o = sub * 4 + i * 16;
        const uint2 w0 = sh[o];
        const uint2 w1 = sh[o + 1];
        const uint2 w2 = sh[o + 2];
        const uint2 w3 = sh[o + 3];
        float4 f;
        f.x = (float)(((rw ? w0.y : w0.x) >> bit) & 1u);
        f.y = (float)(((rw ? w1.y : w1.x) >> bit) & 1u);
        f.z = (float)(((rw ? w2.y : w2.x) >> bit) & 1u);
        f.w = (float)(((rw ? w3.y : w3.x) >> bit) & 1u);
        *(float4*)(op + o) = f;
    }
}

// ---- Fallback 1 (ws fits table but not sp): round-2 quad kernel, direct writes.
__global__ __launch_bounds__(128) void snn_quad_kernel(
    const float* __restrict__ M, const float* __restrict__ tab,
    const float* __restrict__ V0, const float* __restrict__ gs,
    const float* __restrict__ alpha, const float* __restrict__ eta,
    const float* __restrict__ beta, float* __restrict__ out, int T)
{
    const int l = threadIdx.x;
    const int r = blockIdx.x;
    const int c0 = 4 * l;
    const float a = alpha[0], e = eta[0], bt = beta[0];
    const float kk = 0.2f, dd = 0.36787944117144233f, Vth = 0.2f;

    float4 v = *(const float4*)(V0 + (size_t)r * NN + c0);
    const float4 m = *(const float4*)(M + (size_t)r * NN + c0);
    const float4 g4 = *(const float4*)(gs + c0);
    float4 cg;
    cg.x = e * bt * g4.x; cg.y = e * bt * g4.y;
    cg.z = e * bt * g4.z; cg.w = e * bt * g4.w;

    __shared__ uint4 idxq[2][8];
    const float* tb = tab + c0;
    float em = 1.0f;
    int p = 0;

    for (int t = 0; t < T; ++t) {
        float4 u;
        u.x = kk * fmaf(a, v.x, m.x * em);
        u.y = kk * fmaf(a, v.y, m.y * em);
        u.z = kk * fmaf(a, v.z, m.z * em);
        u.w = kk * fmaf(a, v.w, m.w * em);

        float* op = out + (size_t)t * (NN * NN) + (size_t)c0 * NN + r;
        op[0]      = u.x > Vth ? 1.f : 0.f;
        op[NN]     = u.y > Vth ? 1.f : 0.f;
        op[2 * NN] = u.z > Vth ? 1.f : 0.f;
        op[3 * NN] = u.w > Vth ? 1.f : 0.f;

        unsigned idx = (u.x > 0.f ? 1u : 0u) | (u.y > 0.f ? 2u : 0u)
                     | (u.z > 0.f ? 4u : 0u) | (u.w > 0.f ? 8u : 0u);
        ((unsigned char*)&idxq[p][0])[l] = (unsigned char)idx;
        __syncthreads();

        float4 acc = make_float4(0.f, 0.f, 0.f, 0.f);
#pragma unroll
        for (int g = 0; g < 4; ++g) {
            const uint4 wa = idxq[p][2 * g];
            const uint4 wb = idxq[p][2 * g + 1];
            const unsigned wz[8] = {wa.x, wa.y, wa.z, wa.w, wb.x, wb.y, wb.z, wb.w};
#pragma unroll
            for (int d = 0; d < 8; ++d) {
                const unsigned w = wz[d];
#pragma unroll
                for (int k = 0; k < 4; ++k) {
                    const int q = 32 * g + 4 * d + k;
                    const unsigned ibyt = (w >> (8 * k)) & 0xFFu;
                    const float4 tv = *(const float4*)(tb + ((size_t)ibyt << 16) + (q << 9));
                    acc.x += tv.x; acc.y += tv.y; acc.z += tv.z; acc.w += tv.w;
                }
            }
        }

        v.x = fmaf(dd, v.x, fmaf(e, acc.x, cg.x));
        v.y = fmaf(dd, v.y, fmaf(e, acc.y, cg.y));
        v.z = fmaf(dd, v.z, fmaf(e, acc.z, cg.z));
        v.w = fmaf(dd, v.w, fmaf(e, acc.w, cg.w));
        em *= dd;
        p ^= 1;
    }
}

// ---- Fallback 2 (tiny ws): round-1 kernel.
__global__ __launch_bounds__(256) void snn_step_kernel(
    const float* __restrict__ M, const float* __restrict__ G,
    const float* __restrict__ V0, const float* __restrict__ gs,
    const float* __restrict__ alpha, const float* __restrict__ eta,
    const float* __restrict__ beta, float* __restrict__ out, int T)
{
    const int j = threadIdx.x;
    const int r0 = blockIdx.x * 2;
    const int c0 = 2 * j;
    const float a = alpha[0], e = eta[0], bt = beta[0];
    const float kk = 0.2f, dd = 0.36787944117144233f, Vth = 0.2f;

    float v00 = V0[r0 * NN + c0];
    float v01 = V0[r0 * NN + c0 + 1];
    float v10 = V0[(r0 + 1) * NN + c0];
    float v11 = V0[(r0 + 1) * NN + c0 + 1];
    const float m00 = M[r0 * NN + c0];
    const float m01 = M[r0 * NN + c0 + 1];
    const float m10 = M[(r0 + 1) * NN + c0];
    const float m11 = M[(r0 + 1) * NN + c0 + 1];
    const float gs0 = gs[c0];
    const float gs1 = gs[c0 + 1];

    __shared__ float2 hp[NN];
    float em = 1.0f;
    const float2* Gcol = (const float2*)G + j;

    for (int t = 0; t < T; ++t) {
        const float u00 = kk * (m00 * em + a * v00);
        const float u01 = kk * (m01 * em + a * v01);
        const float u10 = kk * (m10 * em + a * v10);
        const float u11 = kk * (m11 * em + a * v11);

        float* outp = out + (size_t)t * (NN * NN);
        float2 sA = make_float2(u00 > Vth ? 1.f : 0.f, u10 > Vth ? 1.f : 0.f);
        float2 sB = make_float2(u01 > Vth ? 1.f : 0.f, u11 > Vth ? 1.f : 0.f);
        *(float2*)(outp + (size_t)c0 * NN + r0) = sA;
        *(float2*)(outp + (size_t)(c0 + 1) * NN + r0) = sB;

        hp[c0]     = make_float2(u00 > 0.f ? 1.f : 0.f, u10 > 0.f ? 1.f : 0.f);
        hp[c0 + 1] = make_float2(u01 > 0.f ? 1.f : 0.f, u11 > 0.f ? 1.f : 0.f);
        __syncthreads();

        float acc00 = 0.f, acc01 = 0.f, acc10 = 0.f, acc11 = 0.f;
#pragma unroll 8
        for (int bp = 0; bp < NN; ++bp) {
            float2 h = hp[bp];
            float2 g = Gcol[(size_t)bp * 256];
            acc00 = fmaf(h.x, g.x, acc00);
            acc01 = fmaf(h.x, g.y, acc01);
            acc10 = fmaf(h.y, g.x, acc10);
            acc11 = fmaf(h.y, g.y, acc11);
        }

        v00 = dd * v00 + e * (acc00 + bt * gs0);
        v01 = dd * v01 + e * (acc01 + bt * gs1);
        v10 = dd * v10 + e * (acc10 + bt * gs0);
        v11 = dd * v11 + e * (acc11 + bt * gs1);
        em *= dd;
        __syncthreads();
    }
}

extern "C" void kernel_launch(void* const* d_in, const int* in_sizes, int n_in,
                              void* d_out, int out_size, void* d_ws, size_t ws_size,
                              hipStream_t stream)
{
    const float* x     = (const float*)d_in[0];
    const float* W     = (const float*)d_in[1];
    const float* bias  = (const float*)d_in[2];
    const float* alpha = (const float*)d_in[3];
    const float* eta   = (const float*)d_in[4];
    const float* beta  = (const float*)d_in[5];
    const float* P0    = (const float*)d_in[6];
    (void)in_sizes; (void)n_in;

    const int T = out_size / (NN * NN);

    float* ws  = (float*)d_ws;
    float* M   = ws;                            // [512,512]
    float* G   = ws + NN * NN;                  // [512,512]
    float* V0  = ws + 2 * NN * NN;              // [512,512]
    float* gsv = ws + 3 * NN * NN;              // [512]
    float* tab = ws + 3 * NN * NN + NN;         // [16][128][512] = 4 MB
    unsigned* sp = (unsigned*)(tab + (size_t)16 * 128 * 512);  // [T][512][16]

    const size_t need_tab = ((size_t)3 * NN * NN + NN + (size_t)16 * 128 * 512) * 4;
    const size_t need_sp  = need_tab + (size_t)T * NN * 16 * 4;

    // prologue: M,V0 in one dual pass; G in a second; colsum
    hipLaunchKernelGGL(gemm32_nt_kernel, dim3(256), dim3(256), 0, stream,
                       W, P0, x, bias, M, V0);
    hipLaunchKernelGGL(gemm32_nt_kernel, dim3(256), dim3(256), 0, stream,
                       x, (const float*)nullptr, x, (const float*)nullptr, G, (float*)nullptr);
    hipLaunchKernelGGL(colsum_kernel, dim3(8), dim3(256), 0, stream, G, gsv);

    if (ws_size >= need_sp) {
        hipLaunchKernelGGL(build_table_kernel, dim3(128), dim3(256), 0, stream, G, tab);
        hipLaunchKernelGGL(snn_delta_kernel, dim3(NN), dim3(512), 0, stream,
                           M, tab, V0, gsv, alpha, eta, beta, sp, T);
        hipLaunchKernelGGL(expand_kernel, dim3(T * 8), dim3(256), 0, stream,
                           sp, (float*)d_out);
    } else if (ws_size >= need_tab) {
        hipLaunchKernelGGL(build_table_kernel, dim3(128), dim3(256), 0, stream, G, tab);
        hipLaunchKernelGGL(snn_quad_kernel, dim3(NN), dim3(128), 0, stream,
                           M, tab, V0, gsv, alpha, eta, beta, (float*)d_out, T);
    } else {
        hipLaunchKernelGGL(snn_step_kernel, dim3(256), dim3(256), 0, stream,
                           M, G, V0, gsv, alpha, eta, beta, (float*)d_out, T);
    }
}